// Round 26
// baseline (81.815 us; speedup 1.0000x reference)
//
#include <hip/hip_runtime.h>

#define NN 50000
#define NE 800000
#define D 64
#define SLICE 64                        // dst nodes per slice block
#define NBLK 782                        // ceil(NN/SLICE) = buckets
#define BCAP 1536                       // per-bucket capacity (mean 1024, >15 sigma)
#define CSTRIDE 4                       // cursor padding: 16 B
#define UVNODES 64                      // nodes per uv block (8 per wave, 8 waves)
#define UVBLK 782                       // ceil(NN/UVNODES)
#define BINBLK 196                      // bin blocks (own dispatch, whole chip)
#define EPB 4096                        // edges per bin block (196*4096 >= 800K)
#define SCRTOT 2304                     // sorted-list capacity
#define CURWORDS (NBLK * CSTRIDE)       // 3128 dwords
#define WS 72                           // W^T row stride (u16): lane*144B is 16B-aligned

typedef int i32x4 __attribute__((ext_vector_type(4)));
typedef float f32x4 __attribute__((ext_vector_type(4)));
typedef unsigned short u16x8 __attribute__((ext_vector_type(8)));

__device__ __forceinline__ float b2f(unsigned short h) {
    unsigned int u = ((unsigned int)h) << 16;
    return __builtin_bit_cast(float, u);
}
__device__ __forceinline__ unsigned short f2bf(float f) {
    unsigned int u = __builtin_bit_cast(unsigned int, f);
    u = (u + 0x7fffu + ((u >> 16) & 1u)) >> 16;
    return (unsigned short)u;
}

// ---------------------------------------------------------------------------
// zero_cursor: zero per-bucket cursors + write the -inf sentinel v-row.
// ---------------------------------------------------------------------------
__global__ __launch_bounds__(256) void zero_cursor(unsigned int* __restrict__ cursor,
                                                   unsigned short* __restrict__ v)
{
    int i = blockIdx.x * 256 + threadIdx.x;
    if (i < CURWORDS) cursor[i] = 0u;
    if (blockIdx.x == 0 && threadIdx.x < 64)
        v[(size_t)NN * D + threadIdx.x] = 0xFF80;       // sentinel row = -inf
}

// ---------------------------------------------------------------------------
// uv_kernel (782 x 512): u/v/res GEMMs — r25's uv path verbatim, own dispatch
// for direct attribution. W^T bf16 in LDS (27.6K) + xs bf16 (8K) = 35.8 KB.
// ---------------------------------------------------------------------------
__global__ __launch_bounds__(512) void uv_kernel(
    const float* __restrict__ x,
    const float* __restrict__ W_edge,
    const float* __restrict__ b_edge,
    const float* __restrict__ W_res,
    const float* __restrict__ b_res,
    unsigned short* __restrict__ u,
    unsigned short* __restrict__ v,
    unsigned short* __restrict__ res)
{
    __shared__ __attribute__((aligned(16))) unsigned short WuT[D * WS];
    __shared__ __attribute__((aligned(16))) unsigned short WvT[D * WS];
    __shared__ __attribute__((aligned(16))) unsigned short WrT[D * WS];
    __shared__ __attribute__((aligned(16))) unsigned short xs[8][D][8];

    const int tid  = threadIdx.x;
    const int lane = tid & 63;
    const int wid  = tid >> 6;              // 0..7

    // stage W transposed as bf16 (coalesced global reads, one-time)
    for (int i = tid; i < D * D; i += 512) {
        int k = i >> 6, c = i & 63;
        float wt = W_edge[i], wb = W_edge[D * D + i];
        WuT[c * WS + k] = f2bf(wt - wb);
        WvT[c * WS + k] = f2bf(wb);
        WrT[c * WS + k] = f2bf(W_res[i]);
    }

    // stage x rows as bf16: lane l holds x[n0+j][l]; pack 8 -> one b128 write
    const int n0  = blockIdx.x * UVNODES + wid * 8;
    const int n0c = (n0 <= NN - 8) ? n0 : (NN - 8);
    {
        u16x8 px;
#pragma unroll
        for (int j = 0; j < 8; ++j)
            px[j] = f2bf(x[(size_t)(n0c + j) * D + lane]);
        *(u16x8*)&xs[wid][lane][0] = px;
    }
    __syncthreads();

    const float be = b_edge[lane];
    const float br = b_res[lane];
    float au[8], av[8], ar[8];
#pragma unroll
    for (int j = 0; j < 8; ++j) { au[j] = be; av[j] = 0.f; ar[j] = br; }

#pragma unroll 1
    for (int kq = 0; kq < 8; ++kq) {        // 8 k's per iteration
        u16x8 wu8 = *(const u16x8*)&WuT[lane * WS + 8 * kq];
        u16x8 wv8 = *(const u16x8*)&WvT[lane * WS + 8 * kq];
        u16x8 wr8 = *(const u16x8*)&WrT[lane * WS + 8 * kq];
#pragma unroll
        for (int t = 0; t < 8; ++t) {
            u16x8 xh = *(const u16x8*)&xs[wid][8 * kq + t][0];  // uniform
            float wu = b2f(wu8[t]);
            float wv = b2f(wv8[t]);
            float wr = b2f(wr8[t]);
#pragma unroll
            for (int j = 0; j < 8; ++j) {
                float s = b2f(xh[j]);
                au[j] += s * wu;
                av[j] += s * wv;
                ar[j] += s * wr;
            }
        }
    }

    if (n0 < NN) {   // NN % 8 == 0 -> all 8 valid when n0 < NN
#pragma unroll
        for (int j = 0; j < 8; ++j) {
            u[(size_t)(n0 + j) * D + lane]   = f2bf(au[j]);
            v[(size_t)(n0 + j) * D + lane]   = f2bf(av[j]);
            res[(size_t)(n0 + j) * D + lane] = f2bf(ar[j]);
        }
    }
}

// ---------------------------------------------------------------------------
// bin_kernel (196 x 512): histogram binning, own dispatch (whole chip, was
// 98 leftover CUs inside pre_fused). LDS 9.4 KB -> high occupancy.
// ---------------------------------------------------------------------------
__global__ __launch_bounds__(512) void bin_kernel(
    const int* __restrict__ ei,
    unsigned int* __restrict__ bins,
    unsigned int* __restrict__ cursor)
{
    __shared__ int hist[NBLK];
    __shared__ int fillb[NBLK];
    __shared__ int baseb[NBLK];

    const int tid = threadIdx.x;
    const int bb  = blockIdx.x;

    for (int i = tid; i < NBLK; i += 512) { hist[i] = 0; fillb[i] = 0; }
    __syncthreads();

    // phase A: LDS histogram (2 passes x 512 threads x int4)
#pragma unroll 1
    for (int t = 0; t < 2; ++t) {
        int e = bb * EPB + t * 2048 + tid * 4;
        if (e < NE) {
            i32x4 d4 = *(const i32x4*)(ei + NE + e);
#pragma unroll
            for (int j = 0; j < 4; ++j)
                atomicAdd(&hist[((unsigned int)d4[j]) >> 6], 1);
        }
    }
    __syncthreads();

    // phase B: one global atomicAdd per touched bucket
    for (int b = tid; b < NBLK; b += 512) {
        int h = hist[b];
        baseb[b] = h ? (int)atomicAdd(&cursor[b * CSTRIDE], (unsigned)h) : 0;
    }
    __syncthreads();

    // phase C: place edges (re-read, L1/L2 hot)
#pragma unroll 1
    for (int t = 0; t < 2; ++t) {
        int e = bb * EPB + t * 2048 + tid * 4;
        if (e < NE) {
            i32x4 s4 = *(const i32x4*)(ei + e);
            i32x4 d4 = *(const i32x4*)(ei + NE + e);
#pragma unroll
            for (int j = 0; j < 4; ++j) {
                unsigned int de = (unsigned int)d4[j];
                unsigned int b  = de >> 6;
                int pos = baseb[b] + atomicAdd(&fillb[b], 1);
                if (pos < BCAP)
                    bins[(size_t)b * BCAP + pos] =
                        (((unsigned int)s4[j]) << 6) | (de & 63u);
            }
        }
    }
}

// ---------------------------------------------------------------------------
// slice: CSR build (all 512 threads) + unroll-1 row loop:
//   m = register max over neighbor v-rows; out = relu(u+m) + res.
// ---------------------------------------------------------------------------
__global__ __launch_bounds__(512) void slice_kernel(
    const unsigned short* __restrict__ u,
    const unsigned short* __restrict__ v,
    const unsigned short* __restrict__ res,
    const unsigned int* __restrict__ bins,
    const unsigned int* __restrict__ cursor,
    float* __restrict__ out)
{
    __shared__ int sorted[SCRTOT];     // src ids, CSR by row
    __shared__ int cntL[64], ofsL[64], fillL[64];

    const int tid  = threadIdx.x;
    const int lane = tid & 63;
    const int wid  = tid >> 6;                 // 0..7
    const int base = blockIdx.x * SLICE;

    if (tid < 64) { cntL[tid] = 0; fillL[tid] = 0; }
    __syncthreads();

    unsigned int cnt = cursor[blockIdx.x * CSTRIDE];
    if (cnt > BCAP) cnt = BCAP;
    const unsigned int* __restrict__ eb = bins + (size_t)blockIdx.x * BCAP;

    // ---- histogram by dst row (all threads) ----
    for (unsigned int i0 = tid; i0 < cnt; i0 += 512)
        atomicAdd(&cntL[eb[i0] & 63u], 1);
    __syncthreads();

    // ---- exclusive prefix scan of x4-rounded counts (wave 0) ----
    if (wid == 0) {
        int a = (cntL[lane] + 3) & ~3;
        int s = a;
#pragma unroll
        for (int off = 1; off < 64; off <<= 1) {
            int t = __shfl_up(s, off);
            if (lane >= off) s += t;
        }
        ofsL[lane] = s - a;
    }
    __syncthreads();

    // ---- scatter into CSR ----
    for (unsigned int i0 = tid; i0 < cnt; i0 += 512) {
        unsigned int e = eb[i0];
        int dl = (int)(e & 63u);
        int pos = ofsL[dl] + atomicAdd(&fillL[dl], 1);
        sorted[pos] = (int)(e >> 6);
    }
    __syncthreads();

    // ---- pad lists to x4 with sentinel (+4 tail for prefetch overread) ----
    if (tid < 64) {
        int c = cntL[tid], o = ofsL[tid];
        int a = (c + 3) & ~3;
        for (int j = c; j < a; ++j) sorted[o + j] = NN;
        if (tid == 63)
            for (int t = 0; t < 4; ++t) sorted[o + a + t] = NN;
    }
    __syncthreads();

    // ---- aggregate + trivial epilogue: 8 rows per wave, lane = column ----
#pragma unroll 1
    for (int i = 0; i < 8; ++i) {
        int r = wid * 8 + i;
        int n = base + r;
        if (n >= NN) break;
        float ur = b2f(u[(size_t)n * D + lane]);
        float rr = b2f(res[(size_t)n * D + lane]);
        const int o = ofsL[r];
        const int a = (cntL[r] + 3) & ~3;
        float m = -__builtin_inff();
        i32x4 idx = *(const i32x4*)&sorted[o];          // uniform broadcast
#pragma unroll 2
        for (int j = 0; j < a; j += 4) {
            i32x4 nx = *(const i32x4*)&sorted[o + j + 4];  // prefetch
            float v0 = b2f(v[(size_t)idx[0] * D + lane]);
            float v1 = b2f(v[(size_t)idx[1] * D + lane]);
            float v2 = b2f(v[(size_t)idx[2] * D + lane]);
            float v3 = b2f(v[(size_t)idx[3] * D + lane]);
            m = fmaxf(m, fmaxf(fmaxf(v0, v1), fmaxf(v2, v3)));
            idx = nx;
        }
        float agg = fmaxf(0.f, ur + m);   // relu; empty row -> -inf -> 0
        out[(size_t)n * D + lane] = agg + rr;
    }
}

extern "C" void kernel_launch(void* const* d_in, const int* in_sizes, int n_in,
                              void* d_out, int out_size, void* d_ws, size_t ws_size,
                              hipStream_t stream) {
    const float* x      = (const float*)d_in[0];
    const int*   ei     = (const int*)d_in[1];
    const float* W_edge = (const float*)d_in[2];
    const float* b_edge = (const float*)d_in[3];
    const float* W_res  = (const float*)d_in[4];
    const float* b_res  = (const float*)d_in[5];
    float* out = (float*)d_out;

    // ws: cursor u32[CURWORDS] (reserve 64KB) | bins u32[NBLK*BCAP] (4.8MB)
    //     | u bf16 (6.4MB) | v bf16 (6.4MB + sentinel row) | res bf16 (6.4MB)
    unsigned int*   cursor = (unsigned int*)d_ws;
    unsigned int*   bins   = (unsigned int*)((char*)d_ws + (1u << 16));
    unsigned short* uu     = (unsigned short*)((char*)d_ws + (1u << 16)
                              + (size_t)NBLK * BCAP * 4);
    unsigned short* vv     = uu + (size_t)NN * D;
    unsigned short* rr     = vv + (size_t)(NN + 1) * D;   // after sentinel row

    zero_cursor<<<(CURWORDS + 255) / 256, 256, 0, stream>>>(cursor, vv);
    bin_kernel<<<BINBLK, 512, 0, stream>>>(ei, bins, cursor);
    uv_kernel<<<UVBLK, 512, 0, stream>>>(x, W_edge, b_edge, W_res, b_res, uu, vv, rr);
    slice_kernel<<<NBLK, 512, 0, stream>>>(uu, vv, rr, bins, cursor, out);
}

// Round 27
// 76.490 us; speedup vs baseline: 1.0696x; 1.0696x over previous
//
#include <hip/hip_runtime.h>

#define NN 50000
#define NE 800000
#define D 64
#define SLICE 64                        // dst nodes per slice block
#define NBLK 782                        // ceil(NN/SLICE) = buckets
#define BCAP 1536                       // per-bucket capacity (mean 1024, >15 sigma)
#define CSTRIDE 4                       // cursor padding: 16 B
#define UVBLK 782                       // uv blocks (64 nodes each)
#define UVNODES 64
#define BINBLK 196                      // bin blocks
#define EPB 4096                        // edges per bin block
#define SCRTOT 2304                     // sorted-list capacity
#define CURWORDS (NBLK * CSTRIDE)       // 3128 dwords
#define FLAGIDX 3200                    // flag dword inside cursor region
#define WS 72                           // W^T row stride (u16): 144B rows, 16B-aligned frags

typedef int i32x4 __attribute__((ext_vector_type(4)));
typedef float f32x4 __attribute__((ext_vector_type(4)));
typedef unsigned short u16x8 __attribute__((ext_vector_type(8)));
typedef __bf16 bf16x8 __attribute__((ext_vector_type(8)));

__device__ __forceinline__ float b2f(unsigned short h) {
    unsigned int u = ((unsigned int)h) << 16;
    return __builtin_bit_cast(float, u);
}
__device__ __forceinline__ unsigned short f2bf(float f) {
    unsigned int u = __builtin_bit_cast(unsigned int, f);
    u = (u + 0x7fffu + ((u >> 16) & 1u)) >> 16;
    return (unsigned short)u;
}

// ---------------------------------------------------------------------------
// zero_cursor: zero cursors + MFMA-check flag + write -inf sentinel v-row.
// ---------------------------------------------------------------------------
__global__ __launch_bounds__(256) void zero_cursor(unsigned int* __restrict__ cursor,
                                                   unsigned short* __restrict__ v)
{
    int i = blockIdx.x * 256 + threadIdx.x;
    if (i < 3264) cursor[i] = 0u;      // covers CURWORDS and FLAGIDX
    if (blockIdx.x == 0 && threadIdx.x < 64)
        v[(size_t)NN * D + threadIdx.x] = 0xFF80;       // sentinel row = -inf
}

// ---------------------------------------------------------------------------
// uv_mfma (782 x 256): u/v/res via mfma_f32_16x16x32_bf16.
//   Layouts per guide (m89 C/D verified; A/B per T2 LDS-frag convention):
//   A: row=lane&15, k=8*(lane>>4)+j ; B: col=lane&15, k=8*(lane>>4)+j ;
//   D: col=lane&15, row=4*(lane>>4)+r.
//   W^T bf16 in LDS (stride 72 u16) -> B-frag = one 16B read; A from global x.
//   Per wave: 16 nodes, 4 ntiles x (6 frag reads + 6 MFMA). 27.6 KB LDS.
//   VERIFIED AT RUNTIME by check_kernel; uv_fixup repairs if layout wrong.
// ---------------------------------------------------------------------------
__global__ __launch_bounds__(256) void uv_mfma(
    const float* __restrict__ x,
    const float* __restrict__ W_edge,
    const float* __restrict__ b_edge,
    const float* __restrict__ W_res,
    const float* __restrict__ b_res,
    unsigned short* __restrict__ u,
    unsigned short* __restrict__ v,
    unsigned short* __restrict__ res)
{
    __shared__ __attribute__((aligned(16))) unsigned short WuT[D * WS];  // (Wtop-Wbot)^T [col][k]
    __shared__ __attribute__((aligned(16))) unsigned short WvT[D * WS];  // Wbot^T
    __shared__ __attribute__((aligned(16))) unsigned short WrT[D * WS];  // W_res^T

    const int tid  = threadIdx.x;
    const int lane = tid & 63;
    const int wid  = tid >> 6;              // 0..3
    const int cr   = lane & 15;             // A-row / B-col within tile
    const int g    = lane >> 4;             // k-group

    // stage W^T bf16 (one-time per block)
    for (int i = tid; i < D * D; i += 256) {
        int k = i >> 6, c = i & 63;
        float wt = W_edge[i], wb = W_edge[D * D + i];
        WuT[c * WS + k] = f2bf(wt - wb);
        WvT[c * WS + k] = f2bf(wb);
        WrT[c * WS + k] = f2bf(W_res[i]);
    }

    // A fragments: wave handles 16 nodes [Mbase, Mbase+16)
    const int Mbase = blockIdx.x * UVNODES + wid * 16;
    const int nA  = Mbase + cr;
    const int nAc = (nA < NN) ? nA : (NN - 1);
    const float* xr = x + (size_t)nAc * D;
    bf16x8 a0, a1;
    {
        f32x4 p0 = *(const f32x4*)(xr + 8 * g);
        f32x4 p1 = *(const f32x4*)(xr + 8 * g + 4);
        f32x4 p2 = *(const f32x4*)(xr + 32 + 8 * g);
        f32x4 p3 = *(const f32x4*)(xr + 32 + 8 * g + 4);
        u16x8 t0, t1;
#pragma unroll
        for (int j = 0; j < 4; ++j) {
            t0[j] = f2bf(p0[j]); t0[4 + j] = f2bf(p1[j]);
            t1[j] = f2bf(p2[j]); t1[4 + j] = f2bf(p3[j]);
        }
        a0 = __builtin_bit_cast(bf16x8, t0);
        a1 = __builtin_bit_cast(bf16x8, t1);
    }
    __syncthreads();

#pragma unroll 1
    for (int nt = 0; nt < 4; ++nt) {
        const int colg = nt * 16 + cr;
        bf16x8 bu0 = __builtin_bit_cast(bf16x8, *(const u16x8*)&WuT[colg * WS + 8 * g]);
        bf16x8 bu1 = __builtin_bit_cast(bf16x8, *(const u16x8*)&WuT[colg * WS + 32 + 8 * g]);
        bf16x8 bv0 = __builtin_bit_cast(bf16x8, *(const u16x8*)&WvT[colg * WS + 8 * g]);
        bf16x8 bv1 = __builtin_bit_cast(bf16x8, *(const u16x8*)&WvT[colg * WS + 32 + 8 * g]);
        bf16x8 br0 = __builtin_bit_cast(bf16x8, *(const u16x8*)&WrT[colg * WS + 8 * g]);
        bf16x8 br1 = __builtin_bit_cast(bf16x8, *(const u16x8*)&WrT[colg * WS + 32 + 8 * g]);
        const float be = b_edge[colg];
        const float bb = b_res[colg];
        f32x4 cu = {be, be, be, be};
        f32x4 cv = {0.f, 0.f, 0.f, 0.f};
        f32x4 cs = {bb, bb, bb, bb};
        cu = __builtin_amdgcn_mfma_f32_16x16x32_bf16(a0, bu0, cu, 0, 0, 0);
        cu = __builtin_amdgcn_mfma_f32_16x16x32_bf16(a1, bu1, cu, 0, 0, 0);
        cv = __builtin_amdgcn_mfma_f32_16x16x32_bf16(a0, bv0, cv, 0, 0, 0);
        cv = __builtin_amdgcn_mfma_f32_16x16x32_bf16(a1, bv1, cv, 0, 0, 0);
        cs = __builtin_amdgcn_mfma_f32_16x16x32_bf16(a0, br0, cs, 0, 0, 0);
        cs = __builtin_amdgcn_mfma_f32_16x16x32_bf16(a1, br1, cs, 0, 0, 0);
#pragma unroll
        for (int r = 0; r < 4; ++r) {
            int nodeS = Mbase + 4 * g + r;        // D row = 4*(lane>>4)+r (m89)
            if (nodeS < NN) {
                size_t o = (size_t)nodeS * D + colg;
                u[o]   = f2bf(cu[r]);
                v[o]   = f2bf(cv[r]);
                res[o] = f2bf(cs[r]);
            }
        }
    }
}

// ---------------------------------------------------------------------------
// check_kernel (1 x 256): recompute u,v for nodes 0..15, all 64 cols, with
// identical bf16 rounding; flag if any entry differs by > 0.06 (layout-wrong
// diffs are O(1)). Deterministic: same inputs -> same flag.
// ---------------------------------------------------------------------------
__global__ __launch_bounds__(256) void check_kernel(
    const float* __restrict__ x,
    const float* __restrict__ W_edge,
    const float* __restrict__ b_edge,
    const unsigned short* __restrict__ u,
    const unsigned short* __restrict__ v,
    unsigned int* __restrict__ flag)
{
    const int lane = threadIdx.x & 63;     // col
    const int wid  = threadIdx.x >> 6;     // node group: nodes 4*wid .. +4
    unsigned int bad = 0;
    for (int i = 0; i < 4; ++i) {
        int n = wid * 4 + i;
        float su = b_edge[lane];
        float sv = 0.f;
        for (int k = 0; k < 64; ++k) {
            float xk = b2f(f2bf(x[(size_t)n * D + k]));
            float wt = W_edge[k * D + lane], wb = W_edge[(D + k) * D + lane];
            su += xk * b2f(f2bf(wt - wb));
            sv += xk * b2f(f2bf(wb));
        }
        if (fabsf(b2f(u[(size_t)n * D + lane]) - su) > 0.06f) bad = 1;
        if (fabsf(b2f(v[(size_t)n * D + lane]) - sv) > 0.06f) bad = 1;
    }
    if (__ballot(bad != 0) != 0ull && lane == 0)
        flag[0] = 1u;                      // racy same-value store: fine
}

// ---------------------------------------------------------------------------
// uv_fixup (782 x 512): r25's proven VALU uv kernel, guarded by the flag.
// No-op (~launch cost) when MFMA layout verified correct.
// ---------------------------------------------------------------------------
__global__ __launch_bounds__(512) void uv_fixup(
    const float* __restrict__ x,
    const float* __restrict__ W_edge,
    const float* __restrict__ b_edge,
    const float* __restrict__ W_res,
    const float* __restrict__ b_res,
    unsigned short* __restrict__ u,
    unsigned short* __restrict__ v,
    unsigned short* __restrict__ res,
    const unsigned int* __restrict__ flag)
{
    if (flag[0] == 0u) return;

    __shared__ __attribute__((aligned(16))) unsigned short WuT[D * WS];
    __shared__ __attribute__((aligned(16))) unsigned short WvT[D * WS];
    __shared__ __attribute__((aligned(16))) unsigned short WrT[D * WS];
    __shared__ __attribute__((aligned(16))) unsigned short xs[8][D][8];

    const int tid  = threadIdx.x;
    const int lane = tid & 63;
    const int wid  = tid >> 6;

    for (int i = tid; i < D * D; i += 512) {
        int k = i >> 6, c = i & 63;
        float wt = W_edge[i], wb = W_edge[D * D + i];
        WuT[c * WS + k] = f2bf(wt - wb);
        WvT[c * WS + k] = f2bf(wb);
        WrT[c * WS + k] = f2bf(W_res[i]);
    }

    const int n0  = blockIdx.x * UVNODES + wid * 8;
    const int n0c = (n0 <= NN - 8) ? n0 : (NN - 8);
    {
        u16x8 px;
#pragma unroll
        for (int j = 0; j < 8; ++j)
            px[j] = f2bf(x[(size_t)(n0c + j) * D + lane]);
        *(u16x8*)&xs[wid][lane][0] = px;
    }
    __syncthreads();

    const float be = b_edge[lane];
    const float br = b_res[lane];
    float au[8], av[8], ar[8];
#pragma unroll
    for (int j = 0; j < 8; ++j) { au[j] = be; av[j] = 0.f; ar[j] = br; }

#pragma unroll 1
    for (int kq = 0; kq < 8; ++kq) {
        u16x8 wu8 = *(const u16x8*)&WuT[lane * WS + 8 * kq];
        u16x8 wv8 = *(const u16x8*)&WvT[lane * WS + 8 * kq];
        u16x8 wr8 = *(const u16x8*)&WrT[lane * WS + 8 * kq];
#pragma unroll
        for (int t = 0; t < 8; ++t) {
            u16x8 xh = *(const u16x8*)&xs[wid][8 * kq + t][0];
            float wu = b2f(wu8[t]);
            float wv = b2f(wv8[t]);
            float wr = b2f(wr8[t]);
#pragma unroll
            for (int j = 0; j < 8; ++j) {
                float s = b2f(xh[j]);
                au[j] += s * wu;
                av[j] += s * wv;
                ar[j] += s * wr;
            }
        }
    }

    if (n0 < NN) {
#pragma unroll
        for (int j = 0; j < 8; ++j) {
            u[(size_t)(n0 + j) * D + lane]   = f2bf(au[j]);
            v[(size_t)(n0 + j) * D + lane]   = f2bf(av[j]);
            res[(size_t)(n0 + j) * D + lane] = f2bf(ar[j]);
        }
    }
}

// ---------------------------------------------------------------------------
// bin_kernel (196 x 512): histogram binning (r26, unchanged).
// ---------------------------------------------------------------------------
__global__ __launch_bounds__(512) void bin_kernel(
    const int* __restrict__ ei,
    unsigned int* __restrict__ bins,
    unsigned int* __restrict__ cursor)
{
    __shared__ int hist[NBLK];
    __shared__ int fillb[NBLK];
    __shared__ int baseb[NBLK];

    const int tid = threadIdx.x;
    const int bb  = blockIdx.x;

    for (int i = tid; i < NBLK; i += 512) { hist[i] = 0; fillb[i] = 0; }
    __syncthreads();

#pragma unroll 1
    for (int t = 0; t < 2; ++t) {
        int e = bb * EPB + t * 2048 + tid * 4;
        if (e < NE) {
            i32x4 d4 = *(const i32x4*)(ei + NE + e);
#pragma unroll
            for (int j = 0; j < 4; ++j)
                atomicAdd(&hist[((unsigned int)d4[j]) >> 6], 1);
        }
    }
    __syncthreads();

    for (int b = tid; b < NBLK; b += 512) {
        int h = hist[b];
        baseb[b] = h ? (int)atomicAdd(&cursor[b * CSTRIDE], (unsigned)h) : 0;
    }
    __syncthreads();

#pragma unroll 1
    for (int t = 0; t < 2; ++t) {
        int e = bb * EPB + t * 2048 + tid * 4;
        if (e < NE) {
            i32x4 s4 = *(const i32x4*)(ei + e);
            i32x4 d4 = *(const i32x4*)(ei + NE + e);
#pragma unroll
            for (int j = 0; j < 4; ++j) {
                unsigned int de = (unsigned int)d4[j];
                unsigned int b  = de >> 6;
                int pos = baseb[b] + atomicAdd(&fillb[b], 1);
                if (pos < BCAP)
                    bins[(size_t)b * BCAP + pos] =
                        (((unsigned int)s4[j]) << 6) | (de & 63u);
            }
        }
    }
}

// ---------------------------------------------------------------------------
// slice: CSR build + unroll-1 row loop; out = relu(u+m) + res. (unchanged)
// ---------------------------------------------------------------------------
__global__ __launch_bounds__(512) void slice_kernel(
    const unsigned short* __restrict__ u,
    const unsigned short* __restrict__ v,
    const unsigned short* __restrict__ res,
    const unsigned int* __restrict__ bins,
    const unsigned int* __restrict__ cursor,
    float* __restrict__ out)
{
    __shared__ int sorted[SCRTOT];
    __shared__ int cntL[64], ofsL[64], fillL[64];

    const int tid  = threadIdx.x;
    const int lane = tid & 63;
    const int wid  = tid >> 6;
    const int base = blockIdx.x * SLICE;

    if (tid < 64) { cntL[tid] = 0; fillL[tid] = 0; }
    __syncthreads();

    unsigned int cnt = cursor[blockIdx.x * CSTRIDE];
    if (cnt > BCAP) cnt = BCAP;
    const unsigned int* __restrict__ eb = bins + (size_t)blockIdx.x * BCAP;

    for (unsigned int i0 = tid; i0 < cnt; i0 += 512)
        atomicAdd(&cntL[eb[i0] & 63u], 1);
    __syncthreads();

    if (wid == 0) {
        int a = (cntL[lane] + 3) & ~3;
        int s = a;
#pragma unroll
        for (int off = 1; off < 64; off <<= 1) {
            int t = __shfl_up(s, off);
            if (lane >= off) s += t;
        }
        ofsL[lane] = s - a;
    }
    __syncthreads();

    for (unsigned int i0 = tid; i0 < cnt; i0 += 512) {
        unsigned int e = eb[i0];
        int dl = (int)(e & 63u);
        int pos = ofsL[dl] + atomicAdd(&fillL[dl], 1);
        sorted[pos] = (int)(e >> 6);
    }
    __syncthreads();

    if (tid < 64) {
        int c = cntL[tid], o = ofsL[tid];
        int a = (c + 3) & ~3;
        for (int j = c; j < a; ++j) sorted[o + j] = NN;
        if (tid == 63)
            for (int t = 0; t < 4; ++t) sorted[o + a + t] = NN;
    }
    __syncthreads();

#pragma unroll 1
    for (int i = 0; i < 8; ++i) {
        int r = wid * 8 + i;
        int n = base + r;
        if (n >= NN) break;
        float ur = b2f(u[(size_t)n * D + lane]);
        float rr = b2f(res[(size_t)n * D + lane]);
        const int o = ofsL[r];
        const int a = (cntL[r] + 3) & ~3;
        float m = -__builtin_inff();
        i32x4 idx = *(const i32x4*)&sorted[o];
#pragma unroll 2
        for (int j = 0; j < a; j += 4) {
            i32x4 nx = *(const i32x4*)&sorted[o + j + 4];
            float v0 = b2f(v[(size_t)idx[0] * D + lane]);
            float v1 = b2f(v[(size_t)idx[1] * D + lane]);
            float v2 = b2f(v[(size_t)idx[2] * D + lane]);
            float v3 = b2f(v[(size_t)idx[3] * D + lane]);
            m = fmaxf(m, fmaxf(fmaxf(v0, v1), fmaxf(v2, v3)));
            idx = nx;
        }
        float agg = fmaxf(0.f, ur + m);
        out[(size_t)n * D + lane] = agg + rr;
    }
}

extern "C" void kernel_launch(void* const* d_in, const int* in_sizes, int n_in,
                              void* d_out, int out_size, void* d_ws, size_t ws_size,
                              hipStream_t stream) {
    const float* x      = (const float*)d_in[0];
    const int*   ei     = (const int*)d_in[1];
    const float* W_edge = (const float*)d_in[2];
    const float* b_edge = (const float*)d_in[3];
    const float* W_res  = (const float*)d_in[4];
    const float* b_res  = (const float*)d_in[5];
    float* out = (float*)d_out;

    // ws: cursor+flag u32 (64KB region) | bins u32[NBLK*BCAP] (4.8MB)
    //     | u bf16 (6.4MB) | v bf16 (6.4MB + sentinel row) | res bf16 (6.4MB)
    unsigned int*   cursor = (unsigned int*)d_ws;
    unsigned int*   flag   = cursor + FLAGIDX;
    unsigned int*   bins   = (unsigned int*)((char*)d_ws + (1u << 16));
    unsigned short* uu     = (unsigned short*)((char*)d_ws + (1u << 16)
                              + (size_t)NBLK * BCAP * 4);
    unsigned short* vv     = uu + (size_t)NN * D;
    unsigned short* rr     = vv + (size_t)(NN + 1) * D;   // after sentinel row

    zero_cursor<<<13, 256, 0, stream>>>(cursor, vv);
    bin_kernel<<<BINBLK, 512, 0, stream>>>(ei, bins, cursor);
    uv_mfma<<<UVBLK, 256, 0, stream>>>(x, W_edge, b_edge, W_res, b_res, uu, vv, rr);
    check_kernel<<<1, 256, 0, stream>>>(x, W_edge, b_edge, uu, vv, flag);
    uv_fixup<<<UVBLK, 512, 0, stream>>>(x, W_edge, b_edge, W_res, b_res, uu, vv, rr, flag);
    slice_kernel<<<NBLK, 512, 0, stream>>>(uu, vv, rr, bins, cursor, out);
}

// Round 28
// 53.900 us; speedup vs baseline: 1.5179x; 1.4191x over previous
//
#include <hip/hip_runtime.h>

#define NN 50000
#define NE 800000
#define D 64
#define SLICE 64                        // dst nodes per slice block
#define NBLK 782                        // ceil(NN/SLICE) = buckets
#define BCAP 1536                       // per-bucket capacity (mean 1024, >15 sigma)
#define CSTRIDE 4                       // cursor padding: 16 B
#define UVBLK 782                       // uv blocks (64 nodes each)
#define UVNODES 64
#define BINBLK 196                      // bin blocks (fused, after uv blocks)
#define EPB 4096                        // edges per bin block
#define SCRTOT 2304                     // sorted-list capacity
#define CURWORDS (NBLK * CSTRIDE)       // 3128 dwords
#define WS 72                           // W^T row stride (u16): 144B rows, 16B-aligned frags

typedef int i32x4 __attribute__((ext_vector_type(4)));
typedef float f32x4 __attribute__((ext_vector_type(4)));
typedef unsigned short u16x8 __attribute__((ext_vector_type(8)));
typedef __bf16 bf16x8 __attribute__((ext_vector_type(8)));

__device__ __forceinline__ float b2f(unsigned short h) {
    unsigned int u = ((unsigned int)h) << 16;
    return __builtin_bit_cast(float, u);
}
__device__ __forceinline__ unsigned short f2bf(float f) {
    unsigned int u = __builtin_bit_cast(unsigned int, f);
    u = (u + 0x7fffu + ((u >> 16) & 1u)) >> 16;
    return (unsigned short)u;
}

// ---------------------------------------------------------------------------
// zero_cursor: zero per-bucket cursors + write the -inf sentinel v-row.
// ---------------------------------------------------------------------------
__global__ __launch_bounds__(256) void zero_cursor(unsigned int* __restrict__ cursor,
                                                   unsigned short* __restrict__ v)
{
    int i = blockIdx.x * 256 + threadIdx.x;
    if (i < CURWORDS) cursor[i] = 0u;
    if (blockIdx.x == 0 && threadIdx.x < 64)
        v[(size_t)NN * D + threadIdx.x] = 0xFF80;       // sentinel row = -inf
}

// ---------------------------------------------------------------------------
// pre_fused (978 x 256): blocks [0, UVBLK) = uv/res GEMMs via MFMA
// (layout RUNTIME-VERIFIED in r27: fixup never fired, total dropped).
//   A: row=lane&15, k=8*(lane>>4)+j ; B: col=lane&15, same k ;
//   D: col=lane&15, row=4*(lane>>4)+r  (m89).
//   W^T bf16 in LDS (stride 72 u16) -> B-frag = one 16B read.
//   Per wave: 16 nodes, 4 ntiles x (6 frag reads + 6 MFMA). 27.6 KB LDS.
// Blocks [UVBLK, 978) = histogram binning (LDS hist -> 1 global atomic per
// touched bucket -> place), LDS aliased into the W buffers.
// ---------------------------------------------------------------------------
__global__ __launch_bounds__(256) void pre_fused(
    const float* __restrict__ x,
    const int* __restrict__ ei,
    const float* __restrict__ W_edge,
    const float* __restrict__ b_edge,
    const float* __restrict__ W_res,
    const float* __restrict__ b_res,
    unsigned short* __restrict__ u,
    unsigned short* __restrict__ v,
    unsigned short* __restrict__ res,
    unsigned int* __restrict__ bins,
    unsigned int* __restrict__ cursor)
{
    __shared__ __attribute__((aligned(16))) unsigned short WuT[D * WS];  // | bin: hist
    __shared__ __attribute__((aligned(16))) unsigned short WvT[D * WS];  // | bin: fill
    __shared__ __attribute__((aligned(16))) unsigned short WrT[D * WS];  // | bin: base

    const int tid  = threadIdx.x;
    const int lane = tid & 63;
    const int wid  = tid >> 6;              // 0..3

    if (blockIdx.x < UVBLK) {
        const int cr = lane & 15;           // A-row / B-col within tile
        const int g  = lane >> 4;           // k-group

        // stage W^T bf16 (one-time per block)
        for (int i = tid; i < D * D; i += 256) {
            int k = i >> 6, c = i & 63;
            float wt = W_edge[i], wb = W_edge[D * D + i];
            WuT[c * WS + k] = f2bf(wt - wb);
            WvT[c * WS + k] = f2bf(wb);
            WrT[c * WS + k] = f2bf(W_res[i]);
        }

        // A fragments: wave handles 16 nodes [Mbase, Mbase+16)
        const int Mbase = blockIdx.x * UVNODES + wid * 16;
        const int nA  = Mbase + cr;
        const int nAc = (nA < NN) ? nA : (NN - 1);
        const float* xr = x + (size_t)nAc * D;
        bf16x8 a0, a1;
        {
            f32x4 p0 = *(const f32x4*)(xr + 8 * g);
            f32x4 p1 = *(const f32x4*)(xr + 8 * g + 4);
            f32x4 p2 = *(const f32x4*)(xr + 32 + 8 * g);
            f32x4 p3 = *(const f32x4*)(xr + 32 + 8 * g + 4);
            u16x8 t0, t1;
#pragma unroll
            for (int j = 0; j < 4; ++j) {
                t0[j] = f2bf(p0[j]); t0[4 + j] = f2bf(p1[j]);
                t1[j] = f2bf(p2[j]); t1[4 + j] = f2bf(p3[j]);
            }
            a0 = __builtin_bit_cast(bf16x8, t0);
            a1 = __builtin_bit_cast(bf16x8, t1);
        }
        __syncthreads();

#pragma unroll 1
        for (int nt = 0; nt < 4; ++nt) {
            const int colg = nt * 16 + cr;
            bf16x8 bu0 = __builtin_bit_cast(bf16x8, *(const u16x8*)&WuT[colg * WS + 8 * g]);
            bf16x8 bu1 = __builtin_bit_cast(bf16x8, *(const u16x8*)&WuT[colg * WS + 32 + 8 * g]);
            bf16x8 bv0 = __builtin_bit_cast(bf16x8, *(const u16x8*)&WvT[colg * WS + 8 * g]);
            bf16x8 bv1 = __builtin_bit_cast(bf16x8, *(const u16x8*)&WvT[colg * WS + 32 + 8 * g]);
            bf16x8 br0 = __builtin_bit_cast(bf16x8, *(const u16x8*)&WrT[colg * WS + 8 * g]);
            bf16x8 br1 = __builtin_bit_cast(bf16x8, *(const u16x8*)&WrT[colg * WS + 32 + 8 * g]);
            const float be = b_edge[colg];
            const float bb = b_res[colg];
            f32x4 cu = {be, be, be, be};
            f32x4 cv = {0.f, 0.f, 0.f, 0.f};
            f32x4 cs = {bb, bb, bb, bb};
            cu = __builtin_amdgcn_mfma_f32_16x16x32_bf16(a0, bu0, cu, 0, 0, 0);
            cu = __builtin_amdgcn_mfma_f32_16x16x32_bf16(a1, bu1, cu, 0, 0, 0);
            cv = __builtin_amdgcn_mfma_f32_16x16x32_bf16(a0, bv0, cv, 0, 0, 0);
            cv = __builtin_amdgcn_mfma_f32_16x16x32_bf16(a1, bv1, cv, 0, 0, 0);
            cs = __builtin_amdgcn_mfma_f32_16x16x32_bf16(a0, br0, cs, 0, 0, 0);
            cs = __builtin_amdgcn_mfma_f32_16x16x32_bf16(a1, br1, cs, 0, 0, 0);
#pragma unroll
            for (int r = 0; r < 4; ++r) {
                int nodeS = Mbase + 4 * g + r;    // D row = 4*(lane>>4)+r (m89)
                if (nodeS < NN) {
                    size_t o = (size_t)nodeS * D + colg;
                    u[o]   = f2bf(cu[r]);
                    v[o]   = f2bf(cv[r]);
                    res[o] = f2bf(cs[r]);
                }
            }
        }
    } else {
        // ---- histogram binning (256 threads) ----
        const int bb = blockIdx.x - UVBLK;
        int* hist  = (int*)WuT;            // [NBLK] (3128 B <= 9216 B)
        int* fillb = (int*)WvT;            // [NBLK]
        int* baseb = (int*)WrT;            // [NBLK]
        for (int i = tid; i < NBLK; i += 256) { hist[i] = 0; fillb[i] = 0; }
        __syncthreads();

        // phase A: LDS histogram (4 passes x 256 threads x int4)
#pragma unroll 1
        for (int t = 0; t < 4; ++t) {
            int e = bb * EPB + t * 1024 + tid * 4;
            if (e < NE) {
                i32x4 d4 = *(const i32x4*)(ei + NE + e);
#pragma unroll
                for (int j = 0; j < 4; ++j)
                    atomicAdd(&hist[((unsigned int)d4[j]) >> 6], 1);
            }
        }
        __syncthreads();

        // phase B: one global atomicAdd per touched bucket
        for (int b = tid; b < NBLK; b += 256) {
            int h = hist[b];
            baseb[b] = h ? (int)atomicAdd(&cursor[b * CSTRIDE], (unsigned)h) : 0;
        }
        __syncthreads();

        // phase C: place edges (re-read, L1/L2 hot)
#pragma unroll 1
        for (int t = 0; t < 4; ++t) {
            int e = bb * EPB + t * 1024 + tid * 4;
            if (e < NE) {
                i32x4 s4 = *(const i32x4*)(ei + e);
                i32x4 d4 = *(const i32x4*)(ei + NE + e);
#pragma unroll
                for (int j = 0; j < 4; ++j) {
                    unsigned int de = (unsigned int)d4[j];
                    unsigned int b  = de >> 6;
                    int pos = baseb[b] + atomicAdd(&fillb[b], 1);
                    if (pos < BCAP)
                        bins[(size_t)b * BCAP + pos] =
                            (((unsigned int)s4[j]) << 6) | (de & 63u);
                }
            }
        }
    }
}

// ---------------------------------------------------------------------------
// slice: CSR build (all 512 threads) + unroll-1 row loop:
//   m = register max over neighbor v-rows; out = relu(u+m) + res.
// ---------------------------------------------------------------------------
__global__ __launch_bounds__(512) void slice_kernel(
    const unsigned short* __restrict__ u,
    const unsigned short* __restrict__ v,
    const unsigned short* __restrict__ res,
    const unsigned int* __restrict__ bins,
    const unsigned int* __restrict__ cursor,
    float* __restrict__ out)
{
    __shared__ int sorted[SCRTOT];     // src ids, CSR by row
    __shared__ int cntL[64], ofsL[64], fillL[64];

    const int tid  = threadIdx.x;
    const int lane = tid & 63;
    const int wid  = tid >> 6;                 // 0..7
    const int base = blockIdx.x * SLICE;

    if (tid < 64) { cntL[tid] = 0; fillL[tid] = 0; }
    __syncthreads();

    unsigned int cnt = cursor[blockIdx.x * CSTRIDE];
    if (cnt > BCAP) cnt = BCAP;
    const unsigned int* __restrict__ eb = bins + (size_t)blockIdx.x * BCAP;

    // ---- histogram by dst row (all threads) ----
    for (unsigned int i0 = tid; i0 < cnt; i0 += 512)
        atomicAdd(&cntL[eb[i0] & 63u], 1);
    __syncthreads();

    // ---- exclusive prefix scan of x4-rounded counts (wave 0) ----
    if (wid == 0) {
        int a = (cntL[lane] + 3) & ~3;
        int s = a;
#pragma unroll
        for (int off = 1; off < 64; off <<= 1) {
            int t = __shfl_up(s, off);
            if (lane >= off) s += t;
        }
        ofsL[lane] = s - a;
    }
    __syncthreads();

    // ---- scatter into CSR ----
    for (unsigned int i0 = tid; i0 < cnt; i0 += 512) {
        unsigned int e = eb[i0];
        int dl = (int)(e & 63u);
        int pos = ofsL[dl] + atomicAdd(&fillL[dl], 1);
        sorted[pos] = (int)(e >> 6);
    }
    __syncthreads();

    // ---- pad lists to x4 with sentinel (+4 tail for prefetch overread) ----
    if (tid < 64) {
        int c = cntL[tid], o = ofsL[tid];
        int a = (c + 3) & ~3;
        for (int j = c; j < a; ++j) sorted[o + j] = NN;
        if (tid == 63)
            for (int t = 0; t < 4; ++t) sorted[o + a + t] = NN;
    }
    __syncthreads();

    // ---- aggregate + trivial epilogue: 8 rows per wave, lane = column ----
#pragma unroll 1
    for (int i = 0; i < 8; ++i) {
        int r = wid * 8 + i;
        int n = base + r;
        if (n >= NN) break;
        float ur = b2f(u[(size_t)n * D + lane]);
        float rr = b2f(res[(size_t)n * D + lane]);
        const int o = ofsL[r];
        const int a = (cntL[r] + 3) & ~3;
        float m = -__builtin_inff();
        i32x4 idx = *(const i32x4*)&sorted[o];          // uniform broadcast
#pragma unroll 2
        for (int j = 0; j < a; j += 4) {
            i32x4 nx = *(const i32x4*)&sorted[o + j + 4];  // prefetch
            float v0 = b2f(v[(size_t)idx[0] * D + lane]);
            float v1 = b2f(v[(size_t)idx[1] * D + lane]);
            float v2 = b2f(v[(size_t)idx[2] * D + lane]);
            float v3 = b2f(v[(size_t)idx[3] * D + lane]);
            m = fmaxf(m, fmaxf(fmaxf(v0, v1), fmaxf(v2, v3)));
            idx = nx;
        }
        float agg = fmaxf(0.f, ur + m);   // relu; empty row -> -inf -> 0
        out[(size_t)n * D + lane] = agg + rr;
    }
}

extern "C" void kernel_launch(void* const* d_in, const int* in_sizes, int n_in,
                              void* d_out, int out_size, void* d_ws, size_t ws_size,
                              hipStream_t stream) {
    const float* x      = (const float*)d_in[0];
    const int*   ei     = (const int*)d_in[1];
    const float* W_edge = (const float*)d_in[2];
    const float* b_edge = (const float*)d_in[3];
    const float* W_res  = (const float*)d_in[4];
    const float* b_res  = (const float*)d_in[5];
    float* out = (float*)d_out;

    // ws: cursor u32[CURWORDS] (reserve 64KB) | bins u32[NBLK*BCAP] (4.8MB)
    //     | u bf16 (6.4MB) | v bf16 (6.4MB + sentinel row) | res bf16 (6.4MB)
    unsigned int*   cursor = (unsigned int*)d_ws;
    unsigned int*   bins   = (unsigned int*)((char*)d_ws + (1u << 16));
    unsigned short* uu     = (unsigned short*)((char*)d_ws + (1u << 16)
                              + (size_t)NBLK * BCAP * 4);
    unsigned short* vv     = uu + (size_t)NN * D;
    unsigned short* rr     = vv + (size_t)(NN + 1) * D;   // after sentinel row

    zero_cursor<<<(CURWORDS + 255) / 256, 256, 0, stream>>>(cursor, vv);
    pre_fused<<<UVBLK + BINBLK, 256, 0, stream>>>(x, ei, W_edge, b_edge, W_res, b_res,
                                                  uu, vv, rr, bins, cursor);
    slice_kernel<<<NBLK, 512, 0, stream>>>(uu, vv, rr, bins, cursor, out);
}

// Round 29
// 52.149 us; speedup vs baseline: 1.5689x; 1.0336x over previous
//
#include <hip/hip_runtime.h>

#define NN 50000
#define NE 800000
#define D 64
#define SLICE 64                        // dst nodes per slice block
#define NBLK 782                        // ceil(NN/SLICE) = buckets
#define BCAP 1536                       // per-bucket capacity (mean 1024, >15 sigma)
#define CSTRIDE 4                       // cursor padding: 16 B
#define UVBLK 782                       // uv blocks (64 nodes each)
#define UVNODES 64
#define BINBLK 196                      // bin blocks (fused, after uv blocks)
#define EPB 4096                        // edges per bin block
#define SCRTOT 2304                     // sorted-list capacity
#define CURWORDS (NBLK * CSTRIDE)       // 3128 dwords
#define WS 72                           // W^T row stride (u16): 144B rows, 16B-aligned frags

typedef int i32x4 __attribute__((ext_vector_type(4)));
typedef float f32x4 __attribute__((ext_vector_type(4)));
typedef unsigned short u16x8 __attribute__((ext_vector_type(8)));
typedef __bf16 bf16x8 __attribute__((ext_vector_type(8)));

__device__ __forceinline__ float b2f(unsigned short h) {
    unsigned int u = ((unsigned int)h) << 16;
    return __builtin_bit_cast(float, u);
}
__device__ __forceinline__ unsigned short f2bf(float f) {
    unsigned int u = __builtin_bit_cast(unsigned int, f);
    u = (u + 0x7fffu + ((u >> 16) & 1u)) >> 16;
    return (unsigned short)u;
}

// ---------------------------------------------------------------------------
// prep_kernel (17 x 256): zero cursors + sentinel v-row + build W^T bf16
// scratch ONCE (was: every one of 782 uv blocks re-read + converted 48 KB).
// ---------------------------------------------------------------------------
__global__ __launch_bounds__(256) void prep_kernel(
    const float* __restrict__ W_edge,
    const float* __restrict__ W_res,
    unsigned int* __restrict__ cursor,
    unsigned short* __restrict__ v,
    unsigned short* __restrict__ wsW)   // [3][D*WS] bf16: Wu^T | Wv^T | Wr^T
{
    const int gtid = blockIdx.x * 256 + threadIdx.x;
    const int gstr = gridDim.x * 256;
    for (int i = gtid; i < CURWORDS; i += gstr) cursor[i] = 0u;
    if (gtid < 64) v[(size_t)NN * D + gtid] = 0xFF80;   // sentinel row = -inf
    for (int i = gtid; i < D * D; i += gstr) {
        int k = i >> 6, c = i & 63;
        float wt = W_edge[i], wb = W_edge[D * D + i];
        wsW[c * WS + k]                = f2bf(wt - wb); // Wu^T
        wsW[D * WS + c * WS + k]       = f2bf(wb);      // Wv^T
        wsW[2 * D * WS + c * WS + k]   = f2bf(W_res[i]);// Wr^T
    }
}

// ---------------------------------------------------------------------------
// pre_fused (978 x 256): blocks [0, UVBLK) = uv/res GEMMs via MFMA, B-frags
// read DIRECTLY from the global W^T bf16 scratch (48 KB, L2-hot) — no LDS,
// no staging, no barrier in the uv path. Layout runtime-verified in r27.
//   A: row=lane&15, k=8*(lane>>4)+j ; B: col=lane&15, same k ;
//   D: col=lane&15, row=4*(lane>>4)+r  (m89).
// Blocks [UVBLK, 978) = histogram binning (9.4 KB LDS).
// ---------------------------------------------------------------------------
__global__ __launch_bounds__(256) void pre_fused(
    const float* __restrict__ x,
    const int* __restrict__ ei,
    const unsigned short* __restrict__ wsW,
    const float* __restrict__ b_edge,
    const float* __restrict__ b_res,
    unsigned short* __restrict__ u,
    unsigned short* __restrict__ v,
    unsigned short* __restrict__ res,
    unsigned int* __restrict__ bins,
    unsigned int* __restrict__ cursor)
{
    __shared__ int histS[NBLK];        // bin path only (9.4 KB total)
    __shared__ int fillS[NBLK];
    __shared__ int baseS[NBLK];

    const int tid  = threadIdx.x;
    const int lane = tid & 63;
    const int wid  = tid >> 6;              // 0..3

    if (blockIdx.x < UVBLK) {
        const int cr = lane & 15;           // A-row / B-col within tile
        const int g  = lane >> 4;           // k-group
        const unsigned short* __restrict__ WuT = wsW;
        const unsigned short* __restrict__ WvT = wsW + D * WS;
        const unsigned short* __restrict__ WrT = wsW + 2 * D * WS;

        // A fragments: wave handles 16 nodes [Mbase, Mbase+16)
        const int Mbase = blockIdx.x * UVNODES + wid * 16;
        const int nA  = Mbase + cr;
        const int nAc = (nA < NN) ? nA : (NN - 1);
        const float* xr = x + (size_t)nAc * D;
        bf16x8 a0, a1;
        {
            f32x4 p0 = *(const f32x4*)(xr + 8 * g);
            f32x4 p1 = *(const f32x4*)(xr + 8 * g + 4);
            f32x4 p2 = *(const f32x4*)(xr + 32 + 8 * g);
            f32x4 p3 = *(const f32x4*)(xr + 32 + 8 * g + 4);
            u16x8 t0, t1;
#pragma unroll
            for (int j = 0; j < 4; ++j) {
                t0[j] = f2bf(p0[j]); t0[4 + j] = f2bf(p1[j]);
                t1[j] = f2bf(p2[j]); t1[4 + j] = f2bf(p3[j]);
            }
            a0 = __builtin_bit_cast(bf16x8, t0);
            a1 = __builtin_bit_cast(bf16x8, t1);
        }

#pragma unroll 1
        for (int nt = 0; nt < 4; ++nt) {
            const int colg = nt * 16 + cr;
            bf16x8 bu0 = __builtin_bit_cast(bf16x8, *(const u16x8*)&WuT[colg * WS + 8 * g]);
            bf16x8 bu1 = __builtin_bit_cast(bf16x8, *(const u16x8*)&WuT[colg * WS + 32 + 8 * g]);
            bf16x8 bv0 = __builtin_bit_cast(bf16x8, *(const u16x8*)&WvT[colg * WS + 8 * g]);
            bf16x8 bv1 = __builtin_bit_cast(bf16x8, *(const u16x8*)&WvT[colg * WS + 32 + 8 * g]);
            bf16x8 br0 = __builtin_bit_cast(bf16x8, *(const u16x8*)&WrT[colg * WS + 8 * g]);
            bf16x8 br1 = __builtin_bit_cast(bf16x8, *(const u16x8*)&WrT[colg * WS + 32 + 8 * g]);
            const float be = b_edge[colg];
            const float bb = b_res[colg];
            f32x4 cu = {be, be, be, be};
            f32x4 cv = {0.f, 0.f, 0.f, 0.f};
            f32x4 cs = {bb, bb, bb, bb};
            cu = __builtin_amdgcn_mfma_f32_16x16x32_bf16(a0, bu0, cu, 0, 0, 0);
            cu = __builtin_amdgcn_mfma_f32_16x16x32_bf16(a1, bu1, cu, 0, 0, 0);
            cv = __builtin_amdgcn_mfma_f32_16x16x32_bf16(a0, bv0, cv, 0, 0, 0);
            cv = __builtin_amdgcn_mfma_f32_16x16x32_bf16(a1, bv1, cv, 0, 0, 0);
            cs = __builtin_amdgcn_mfma_f32_16x16x32_bf16(a0, br0, cs, 0, 0, 0);
            cs = __builtin_amdgcn_mfma_f32_16x16x32_bf16(a1, br1, cs, 0, 0, 0);
#pragma unroll
            for (int r = 0; r < 4; ++r) {
                int nodeS = Mbase + 4 * g + r;    // D row = 4*(lane>>4)+r (m89)
                if (nodeS < NN) {
                    size_t o = (size_t)nodeS * D + colg;
                    u[o]   = f2bf(cu[r]);
                    v[o]   = f2bf(cv[r]);
                    res[o] = f2bf(cs[r]);
                }
            }
        }
    } else {
        // ---- histogram binning (256 threads) ----
        const int bb = blockIdx.x - UVBLK;
        for (int i = tid; i < NBLK; i += 256) { histS[i] = 0; fillS[i] = 0; }
        __syncthreads();

        // phase A: LDS histogram (4 passes x 256 threads x int4)
#pragma unroll 1
        for (int t = 0; t < 4; ++t) {
            int e = bb * EPB + t * 1024 + tid * 4;
            if (e < NE) {
                i32x4 d4 = *(const i32x4*)(ei + NE + e);
#pragma unroll
                for (int j = 0; j < 4; ++j)
                    atomicAdd(&histS[((unsigned int)d4[j]) >> 6], 1);
            }
        }
        __syncthreads();

        // phase B: one global atomicAdd per touched bucket
        for (int b = tid; b < NBLK; b += 256) {
            int h = histS[b];
            baseS[b] = h ? (int)atomicAdd(&cursor[b * CSTRIDE], (unsigned)h) : 0;
        }
        __syncthreads();

        // phase C: place edges (re-read, L1/L2 hot)
#pragma unroll 1
        for (int t = 0; t < 4; ++t) {
            int e = bb * EPB + t * 1024 + tid * 4;
            if (e < NE) {
                i32x4 s4 = *(const i32x4*)(ei + e);
                i32x4 d4 = *(const i32x4*)(ei + NE + e);
#pragma unroll
                for (int j = 0; j < 4; ++j) {
                    unsigned int de = (unsigned int)d4[j];
                    unsigned int b  = de >> 6;
                    int pos = baseS[b] + atomicAdd(&fillS[b], 1);
                    if (pos < BCAP)
                        bins[(size_t)b * BCAP + pos] =
                            (((unsigned int)s4[j]) << 6) | (de & 63u);
                }
            }
        }
    }
}

// ---------------------------------------------------------------------------
// slice: CSR build (all 512 threads) + unroll-1 row loop:
//   m = register max over neighbor v-rows; out = relu(u+m) + res.
// ---------------------------------------------------------------------------
__global__ __launch_bounds__(512) void slice_kernel(
    const unsigned short* __restrict__ u,
    const unsigned short* __restrict__ v,
    const unsigned short* __restrict__ res,
    const unsigned int* __restrict__ bins,
    const unsigned int* __restrict__ cursor,
    float* __restrict__ out)
{
    __shared__ int sorted[SCRTOT];     // src ids, CSR by row
    __shared__ int cntL[64], ofsL[64], fillL[64];

    const int tid  = threadIdx.x;
    const int lane = tid & 63;
    const int wid  = tid >> 6;                 // 0..7
    const int base = blockIdx.x * SLICE;

    if (tid < 64) { cntL[tid] = 0; fillL[tid] = 0; }
    __syncthreads();

    unsigned int cnt = cursor[blockIdx.x * CSTRIDE];
    if (cnt > BCAP) cnt = BCAP;
    const unsigned int* __restrict__ eb = bins + (size_t)blockIdx.x * BCAP;

    // ---- histogram by dst row (all threads) ----
    for (unsigned int i0 = tid; i0 < cnt; i0 += 512)
        atomicAdd(&cntL[eb[i0] & 63u], 1);
    __syncthreads();

    // ---- exclusive prefix scan of x4-rounded counts (wave 0) ----
    if (wid == 0) {
        int a = (cntL[lane] + 3) & ~3;
        int s = a;
#pragma unroll
        for (int off = 1; off < 64; off <<= 1) {
            int t = __shfl_up(s, off);
            if (lane >= off) s += t;
        }
        ofsL[lane] = s - a;
    }
    __syncthreads();

    // ---- scatter into CSR ----
    for (unsigned int i0 = tid; i0 < cnt; i0 += 512) {
        unsigned int e = eb[i0];
        int dl = (int)(e & 63u);
        int pos = ofsL[dl] + atomicAdd(&fillL[dl], 1);
        sorted[pos] = (int)(e >> 6);
    }
    __syncthreads();

    // ---- pad lists to x4 with sentinel (+4 tail for prefetch overread) ----
    if (tid < 64) {
        int c = cntL[tid], o = ofsL[tid];
        int a = (c + 3) & ~3;
        for (int j = c; j < a; ++j) sorted[o + j] = NN;
        if (tid == 63)
            for (int t = 0; t < 4; ++t) sorted[o + a + t] = NN;
    }
    __syncthreads();

    // ---- aggregate + trivial epilogue: 8 rows per wave, lane = column ----
#pragma unroll 1
    for (int i = 0; i < 8; ++i) {
        int r = wid * 8 + i;
        int n = base + r;
        if (n >= NN) break;
        float ur = b2f(u[(size_t)n * D + lane]);
        float rr = b2f(res[(size_t)n * D + lane]);
        const int o = ofsL[r];
        const int a = (cntL[r] + 3) & ~3;
        float m = -__builtin_inff();
        i32x4 idx = *(const i32x4*)&sorted[o];          // uniform broadcast
#pragma unroll 2
        for (int j = 0; j < a; j += 4) {
            i32x4 nx = *(const i32x4*)&sorted[o + j + 4];  // prefetch
            float v0 = b2f(v[(size_t)idx[0] * D + lane]);
            float v1 = b2f(v[(size_t)idx[1] * D + lane]);
            float v2 = b2f(v[(size_t)idx[2] * D + lane]);
            float v3 = b2f(v[(size_t)idx[3] * D + lane]);
            m = fmaxf(m, fmaxf(fmaxf(v0, v1), fmaxf(v2, v3)));
            idx = nx;
        }
        float agg = fmaxf(0.f, ur + m);   // relu; empty row -> -inf -> 0
        out[(size_t)n * D + lane] = agg + rr;
    }
}

extern "C" void kernel_launch(void* const* d_in, const int* in_sizes, int n_in,
                              void* d_out, int out_size, void* d_ws, size_t ws_size,
                              hipStream_t stream) {
    const float* x      = (const float*)d_in[0];
    const int*   ei     = (const int*)d_in[1];
    const float* W_edge = (const float*)d_in[2];
    const float* b_edge = (const float*)d_in[3];
    const float* W_res  = (const float*)d_in[4];
    const float* b_res  = (const float*)d_in[5];
    float* out = (float*)d_out;

    // ws: cursor u32[CURWORDS] (16KB) | wsW bf16[3*D*WS] (27.6KB, to 48KB)
    //     | bins u32[NBLK*BCAP] (4.8MB, from 64KB) | u bf16 (6.4MB)
    //     | v bf16 (6.4MB + sentinel) | res bf16 (6.4MB)
    unsigned int*   cursor = (unsigned int*)d_ws;
    unsigned short* wsW    = (unsigned short*)((char*)d_ws + (1u << 14));
    unsigned int*   bins   = (unsigned int*)((char*)d_ws + (1u << 16));
    unsigned short* uu     = (unsigned short*)((char*)d_ws + (1u << 16)
                              + (size_t)NBLK * BCAP * 4);
    unsigned short* vv     = uu + (size_t)NN * D;
    unsigned short* rr     = vv + (size_t)(NN + 1) * D;   // after sentinel row

    prep_kernel<<<17, 256, 0, stream>>>(W_edge, W_res, cursor, vv, wsW);
    pre_fused<<<UVBLK + BINBLK, 256, 0, stream>>>(x, ei, wsW, b_edge, b_res,
                                                  uu, vv, rr, bins, cursor);
    slice_kernel<<<NBLK, 512, 0, stream>>>(uu, vv, rr, bins, cursor, out);
}

// Round 30
// 50.572 us; speedup vs baseline: 1.6178x; 1.0312x over previous
//
#include <hip/hip_runtime.h>

#define NN 50000
#define NE 800000
#define D 64
#define SLICE 64                        // dst nodes per slice block
#define NBLK 782                        // ceil(NN/SLICE) = buckets
#define BCAP 1536                       // per-bucket capacity (mean 1024, >15 sigma)
#define CSTRIDE 4                       // cursor padding: 16 B
#define UVBLK 782                       // uv blocks (64 nodes each)
#define UVNODES 64
#define BINBLK 196                      // bin blocks (fused, after uv blocks)
#define EPB 4096                        // edges per bin block
#define SCRTOT 2304                     // sorted-list capacity
#define CURWORDS (NBLK * CSTRIDE)       // 3128 dwords
#define WS 72                           // W^T row stride (u16): 144B rows, 16B-aligned frags

typedef int i32x4 __attribute__((ext_vector_type(4)));
typedef float f32x4 __attribute__((ext_vector_type(4)));
typedef unsigned short u16x8 __attribute__((ext_vector_type(8)));
typedef __bf16 bf16x8 __attribute__((ext_vector_type(8)));

__device__ __forceinline__ float b2f(unsigned short h) {
    unsigned int u = ((unsigned int)h) << 16;
    return __builtin_bit_cast(float, u);
}
__device__ __forceinline__ unsigned short f2bf(float f) {
    unsigned int u = __builtin_bit_cast(unsigned int, f);
    u = (u + 0x7fffu + ((u >> 16) & 1u)) >> 16;
    return (unsigned short)u;
}

// ---------------------------------------------------------------------------
// prep_kernel (17 x 256): zero cursors + sentinel v-row + build W^T bf16
// scratch once.
// ---------------------------------------------------------------------------
__global__ __launch_bounds__(256) void prep_kernel(
    const float* __restrict__ W_edge,
    const float* __restrict__ W_res,
    unsigned int* __restrict__ cursor,
    unsigned short* __restrict__ v,
    unsigned short* __restrict__ wsW)   // [3][D*WS] bf16: Wu^T | Wv^T | Wr^T
{
    const int gtid = blockIdx.x * 256 + threadIdx.x;
    const int gstr = gridDim.x * 256;
    for (int i = gtid; i < CURWORDS; i += gstr) cursor[i] = 0u;
    if (gtid < 64) v[(size_t)NN * D + gtid] = 0xFF80;   // sentinel row = -inf
    for (int i = gtid; i < D * D; i += gstr) {
        int k = i >> 6, c = i & 63;
        float wt = W_edge[i], wb = W_edge[D * D + i];
        wsW[c * WS + k]                = f2bf(wt - wb); // Wu^T
        wsW[D * WS + c * WS + k]       = f2bf(wb);      // Wv^T
        wsW[2 * D * WS + c * WS + k]   = f2bf(W_res[i]);// Wr^T
    }
}

// ---------------------------------------------------------------------------
// pre_fused (978 x 256): blocks [0, UVBLK) = uv/res GEMMs via MFMA, B-frags
// from global W^T bf16 scratch (L2-hot). u and res PACKED into one u32
// array (ur = res<<16 | u): 32 stores/thread (64B segments) vs 48 (32B).
// nt-loop unroll 2: 12 B-frag loads in flight (~75 VGPR peak, no spill).
// Blocks [UVBLK, 978) = histogram binning (9.4 KB LDS).
// ---------------------------------------------------------------------------
__global__ __launch_bounds__(256) void pre_fused(
    const float* __restrict__ x,
    const int* __restrict__ ei,
    const unsigned short* __restrict__ wsW,
    const float* __restrict__ b_edge,
    const float* __restrict__ b_res,
    unsigned int* __restrict__ ur,
    unsigned short* __restrict__ v,
    unsigned int* __restrict__ bins,
    unsigned int* __restrict__ cursor)
{
    __shared__ int histS[NBLK];        // bin path only (9.4 KB total)
    __shared__ int fillS[NBLK];
    __shared__ int baseS[NBLK];

    const int tid  = threadIdx.x;
    const int lane = tid & 63;
    const int wid  = tid >> 6;              // 0..3

    if (blockIdx.x < UVBLK) {
        const int cr = lane & 15;           // A-row / B-col within tile
        const int g  = lane >> 4;           // k-group
        const unsigned short* __restrict__ WuT = wsW;
        const unsigned short* __restrict__ WvT = wsW + D * WS;
        const unsigned short* __restrict__ WrT = wsW + 2 * D * WS;

        // A fragments: wave handles 16 nodes [Mbase, Mbase+16)
        const int Mbase = blockIdx.x * UVNODES + wid * 16;
        const int nA  = Mbase + cr;
        const int nAc = (nA < NN) ? nA : (NN - 1);
        const float* xr = x + (size_t)nAc * D;
        bf16x8 a0, a1;
        {
            f32x4 p0 = *(const f32x4*)(xr + 8 * g);
            f32x4 p1 = *(const f32x4*)(xr + 8 * g + 4);
            f32x4 p2 = *(const f32x4*)(xr + 32 + 8 * g);
            f32x4 p3 = *(const f32x4*)(xr + 32 + 8 * g + 4);
            u16x8 t0, t1;
#pragma unroll
            for (int j = 0; j < 4; ++j) {
                t0[j] = f2bf(p0[j]); t0[4 + j] = f2bf(p1[j]);
                t1[j] = f2bf(p2[j]); t1[4 + j] = f2bf(p3[j]);
            }
            a0 = __builtin_bit_cast(bf16x8, t0);
            a1 = __builtin_bit_cast(bf16x8, t1);
        }

#pragma unroll 2
        for (int nt = 0; nt < 4; ++nt) {
            const int colg = nt * 16 + cr;
            bf16x8 bu0 = __builtin_bit_cast(bf16x8, *(const u16x8*)&WuT[colg * WS + 8 * g]);
            bf16x8 bu1 = __builtin_bit_cast(bf16x8, *(const u16x8*)&WuT[colg * WS + 32 + 8 * g]);
            bf16x8 bv0 = __builtin_bit_cast(bf16x8, *(const u16x8*)&WvT[colg * WS + 8 * g]);
            bf16x8 bv1 = __builtin_bit_cast(bf16x8, *(const u16x8*)&WvT[colg * WS + 32 + 8 * g]);
            bf16x8 br0 = __builtin_bit_cast(bf16x8, *(const u16x8*)&WrT[colg * WS + 8 * g]);
            bf16x8 br1 = __builtin_bit_cast(bf16x8, *(const u16x8*)&WrT[colg * WS + 32 + 8 * g]);
            const float be = b_edge[colg];
            const float bb = b_res[colg];
            f32x4 cu = {be, be, be, be};
            f32x4 cv = {0.f, 0.f, 0.f, 0.f};
            f32x4 cs = {bb, bb, bb, bb};
            cu = __builtin_amdgcn_mfma_f32_16x16x32_bf16(a0, bu0, cu, 0, 0, 0);
            cu = __builtin_amdgcn_mfma_f32_16x16x32_bf16(a1, bu1, cu, 0, 0, 0);
            cv = __builtin_amdgcn_mfma_f32_16x16x32_bf16(a0, bv0, cv, 0, 0, 0);
            cv = __builtin_amdgcn_mfma_f32_16x16x32_bf16(a1, bv1, cv, 0, 0, 0);
            cs = __builtin_amdgcn_mfma_f32_16x16x32_bf16(a0, br0, cs, 0, 0, 0);
            cs = __builtin_amdgcn_mfma_f32_16x16x32_bf16(a1, br1, cs, 0, 0, 0);
#pragma unroll
            for (int r = 0; r < 4; ++r) {
                int nodeS = Mbase + 4 * g + r;    // D row = 4*(lane>>4)+r (m89)
                if (nodeS < NN) {
                    size_t o = (size_t)nodeS * D + colg;
                    ur[o] = ((unsigned int)f2bf(cs[r]) << 16) | f2bf(cu[r]);
                    v[o]  = f2bf(cv[r]);
                }
            }
        }
    } else {
        // ---- histogram binning (256 threads) ----
        const int bb = blockIdx.x - UVBLK;
        for (int i = tid; i < NBLK; i += 256) { histS[i] = 0; fillS[i] = 0; }
        __syncthreads();

        // phase A: LDS histogram (4 passes x 256 threads x int4)
#pragma unroll 1
        for (int t = 0; t < 4; ++t) {
            int e = bb * EPB + t * 1024 + tid * 4;
            if (e < NE) {
                i32x4 d4 = *(const i32x4*)(ei + NE + e);
#pragma unroll
                for (int j = 0; j < 4; ++j)
                    atomicAdd(&histS[((unsigned int)d4[j]) >> 6], 1);
            }
        }
        __syncthreads();

        // phase B: one global atomicAdd per touched bucket
        for (int b = tid; b < NBLK; b += 256) {
            int h = histS[b];
            baseS[b] = h ? (int)atomicAdd(&cursor[b * CSTRIDE], (unsigned)h) : 0;
        }
        __syncthreads();

        // phase C: place edges (re-read, L1/L2 hot)
#pragma unroll 1
        for (int t = 0; t < 4; ++t) {
            int e = bb * EPB + t * 1024 + tid * 4;
            if (e < NE) {
                i32x4 s4 = *(const i32x4*)(ei + e);
                i32x4 d4 = *(const i32x4*)(ei + NE + e);
#pragma unroll
                for (int j = 0; j < 4; ++j) {
                    unsigned int de = (unsigned int)d4[j];
                    unsigned int b  = de >> 6;
                    int pos = baseS[b] + atomicAdd(&fillS[b], 1);
                    if (pos < BCAP)
                        bins[(size_t)b * BCAP + pos] =
                            (((unsigned int)s4[j]) << 6) | (de & 63u);
                }
            }
        }
    }
}

// ---------------------------------------------------------------------------
// slice: CSR build (all 512 threads) + unroll-1 row loop:
//   m = register max over neighbor v-rows; out = relu(u+m) + res,
//   with u/res unpacked from one u32 load.
// ---------------------------------------------------------------------------
__global__ __launch_bounds__(512) void slice_kernel(
    const unsigned int* __restrict__ ur,
    const unsigned short* __restrict__ v,
    const unsigned int* __restrict__ bins,
    const unsigned int* __restrict__ cursor,
    float* __restrict__ out)
{
    __shared__ int sorted[SCRTOT];     // src ids, CSR by row
    __shared__ int cntL[64], ofsL[64], fillL[64];

    const int tid  = threadIdx.x;
    const int lane = tid & 63;
    const int wid  = tid >> 6;                 // 0..7
    const int base = blockIdx.x * SLICE;

    if (tid < 64) { cntL[tid] = 0; fillL[tid] = 0; }
    __syncthreads();

    unsigned int cnt = cursor[blockIdx.x * CSTRIDE];
    if (cnt > BCAP) cnt = BCAP;
    const unsigned int* __restrict__ eb = bins + (size_t)blockIdx.x * BCAP;

    // ---- histogram by dst row (all threads) ----
    for (unsigned int i0 = tid; i0 < cnt; i0 += 512)
        atomicAdd(&cntL[eb[i0] & 63u], 1);
    __syncthreads();

    // ---- exclusive prefix scan of x4-rounded counts (wave 0) ----
    if (wid == 0) {
        int a = (cntL[lane] + 3) & ~3;
        int s = a;
#pragma unroll
        for (int off = 1; off < 64; off <<= 1) {
            int t = __shfl_up(s, off);
            if (lane >= off) s += t;
        }
        ofsL[lane] = s - a;
    }
    __syncthreads();

    // ---- scatter into CSR ----
    for (unsigned int i0 = tid; i0 < cnt; i0 += 512) {
        unsigned int e = eb[i0];
        int dl = (int)(e & 63u);
        int pos = ofsL[dl] + atomicAdd(&fillL[dl], 1);
        sorted[pos] = (int)(e >> 6);
    }
    __syncthreads();

    // ---- pad lists to x4 with sentinel (+4 tail for prefetch overread) ----
    if (tid < 64) {
        int c = cntL[tid], o = ofsL[tid];
        int a = (c + 3) & ~3;
        for (int j = c; j < a; ++j) sorted[o + j] = NN;
        if (tid == 63)
            for (int t = 0; t < 4; ++t) sorted[o + a + t] = NN;
    }
    __syncthreads();

    // ---- aggregate + trivial epilogue: 8 rows per wave, lane = column ----
#pragma unroll 1
    for (int i = 0; i < 8; ++i) {
        int r = wid * 8 + i;
        int n = base + r;
        if (n >= NN) break;
        unsigned int w = ur[(size_t)n * D + lane];
        float uu2 = b2f((unsigned short)(w & 0xFFFFu));
        float rr  = b2f((unsigned short)(w >> 16));
        const int o = ofsL[r];
        const int a = (cntL[r] + 3) & ~3;
        float m = -__builtin_inff();
        i32x4 idx = *(const i32x4*)&sorted[o];          // uniform broadcast
#pragma unroll 2
        for (int j = 0; j < a; j += 4) {
            i32x4 nx = *(const i32x4*)&sorted[o + j + 4];  // prefetch
            float v0 = b2f(v[(size_t)idx[0] * D + lane]);
            float v1 = b2f(v[(size_t)idx[1] * D + lane]);
            float v2 = b2f(v[(size_t)idx[2] * D + lane]);
            float v3 = b2f(v[(size_t)idx[3] * D + lane]);
            m = fmaxf(m, fmaxf(fmaxf(v0, v1), fmaxf(v2, v3)));
            idx = nx;
        }
        float agg = fmaxf(0.f, uu2 + m);  // relu; empty row -> -inf -> 0
        out[(size_t)n * D + lane] = agg + rr;
    }
}

extern "C" void kernel_launch(void* const* d_in, const int* in_sizes, int n_in,
                              void* d_out, int out_size, void* d_ws, size_t ws_size,
                              hipStream_t stream) {
    const float* x      = (const float*)d_in[0];
    const int*   ei     = (const int*)d_in[1];
    const float* W_edge = (const float*)d_in[2];
    const float* b_edge = (const float*)d_in[3];
    const float* W_res  = (const float*)d_in[4];
    const float* b_res  = (const float*)d_in[5];
    float* out = (float*)d_out;

    // ws: cursor u32[CURWORDS] (16KB) | wsW bf16[3*D*WS] (27.6KB, to 48KB)
    //     | bins u32[NBLK*BCAP] (4.8MB, from 64KB)
    //     | ur u32[NN*D] (12.8MB) | v bf16 (6.4MB + sentinel row)
    unsigned int*   cursor = (unsigned int*)d_ws;
    unsigned short* wsW    = (unsigned short*)((char*)d_ws + (1u << 14));
    unsigned int*   bins   = (unsigned int*)((char*)d_ws + (1u << 16));
    unsigned int*   urr    = (unsigned int*)((char*)d_ws + (1u << 16)
                              + (size_t)NBLK * BCAP * 4);
    unsigned short* vv     = (unsigned short*)(urr + (size_t)NN * D);

    prep_kernel<<<17, 256, 0, stream>>>(W_edge, W_res, cursor, vv, wsW);
    pre_fused<<<UVBLK + BINBLK, 256, 0, stream>>>(x, ei, wsW, b_edge, b_res,
                                                  urr, vv, bins, cursor);
    slice_kernel<<<NBLK, 512, 0, stream>>>(urr, vv, bins, cursor, out);
}